// Round 4
// baseline (356.253 us; speedup 1.0000x reference)
//
#include <hip/hip_runtime.h>
#include <hip/hip_bf16.h>

typedef __attribute__((ext_vector_type(8))) short bf16x8_t;
typedef __attribute__((ext_vector_type(4))) float f32x4_t;

#define XP_BYTES 55115776u   // 4*16*58*58*128*2
#define WT_BYTES 2359296u    // 4*2*256*576*2  (hl-dedup'd)

typedef __attribute__((address_space(1))) const unsigned int ga_u32_t;
typedef __attribute__((address_space(3))) unsigned int lds_u32_t;

__device__ __forceinline__ void g2l16(const void* g, void* l) {
  __builtin_amdgcn_global_load_lds((ga_u32_t*)g, (lds_u32_t*)l, 16, 0, 0);
}

// ---------------------------------------------------------------------------
// prep_x: x (16,256,56,56) f32  ->  xp (4,16,58,58,128) bf16, inner = hl*64+c
// borders zeroed by hipMemsetAsync before this kernel.
// ---------------------------------------------------------------------------
__global__ __launch_bounds__(256) void prep_x(const float* __restrict__ x,
                                              __hip_bfloat16* __restrict__ xp) {
  __shared__ float ls[64 * 57];
  int blk = blockIdx.x;            // (g, b, h) : 4*16*56 = 3584
  int g = blk / 896;
  int r = blk - g * 896;
  int b = r / 56;
  int h = r - b * 56;
  int tid = threadIdx.x;
  const float* src = x + (size_t)(b * 256 + g * 64) * 3136 + h * 56;
  for (int i = tid; i < 64 * 56; i += 256) {
    int c = i / 56, w = i - c * 56;
    ls[c * 57 + w] = src[(size_t)c * 3136 + w];
  }
  __syncthreads();
  __hip_bfloat16* dst = xp + ((size_t)((g * 16 + b) * 58 + h + 1) * 58 + 1) * 128;
  int wp = tid >> 7;
  int inner = tid & 127;
  int hl = inner >> 6, c = inner & 63;
  for (int w0 = 0; w0 < 56; w0 += 2) {
    int w = w0 + wp;
    float v = ls[c * 57 + w];
    __hip_bfloat16 hi = __float2bfloat16(v);
    __hip_bfloat16 val = hl ? __float2bfloat16(v - __bfloat162float(hi)) : hi;
    dst[(size_t)w * 128 + inner] = val;
  }
}

// ---------------------------------------------------------------------------
// prep_w: weight (256,256,3,3) f32 -> wt[g][sign][oc 256][tap 9][c 64] bf16
// integer quant levels 0..3 (exact in bf16). NO hl duplication (K=576/gs).
// ---------------------------------------------------------------------------
__global__ __launch_bounds__(256) void prep_w(const float* __restrict__ wgt,
                                              const float* __restrict__ wsc,
                                              __hip_bfloat16* __restrict__ wt) {
  int idx = blockIdx.x * 256 + threadIdx.x;   // 589824 = 256oc*256C*9tap
  if (idx >= 589824) return;
  int oc = idx / 2304;
  int r = idx - oc * 2304;
  int C = r / 9;
  int tap = r - C * 9;
  int g = C >> 6, c = C & 63;
  float s = wsc[g];
  float rv = wgt[idx] / s;
  float ip = rintf(fminf(fmaxf(rv, 0.f), 3.f));
  float iN = rintf(fminf(fmaxf(-rv, 0.f), 3.f));
  size_t base_p = (size_t)((g * 2 + 0) * 256 + oc) * 576 + tap * 64 + c;
  size_t base_n = (size_t)((g * 2 + 1) * 256 + oc) * 576 + tap * 64 + c;
  wt[base_p] = __float2bfloat16(ip);
  wt[base_n] = __float2bfloat16(iN);
}

// ---------------------------------------------------------------------------
// Main conv. Grid 400 = 16 b x 25 m-tiles (128 px, batch-local, last partial).
// BM=128 px, BN=256 oc. 512 thr = 8 waves (2M x 4N), wave 64x64.
// A: 6-row halo strip (348 px x 256B = 87KB) staged ONCE per group; all 9
//    tap shifts are LDS offsets. hl planes share B (B-frag reused for hi+lo).
// B: 16KB (sign,tap,c32) chunks, triple-buffered, counted vmcnt(2).
// Unit = (g,sign,tap,cc): 12 ds_read_b128 + 32 MFMA; 144 units.
// XOR swizzles: A chunk^(px&7); B slot^(row&3) — on stage-source AND read.
// ---------------------------------------------------------------------------
#define MEMPIN asm volatile("" ::: "memory")
#define BAR __builtin_amdgcn_s_barrier()
#define VMCNT2 asm volatile("s_waitcnt vmcnt(2)" ::: "memory")
#define VMCNT0 asm volatile("s_waitcnt vmcnt(0)" ::: "memory")

__global__ __launch_bounds__(512, 2) void conv_mfma(
    const unsigned short* __restrict__ xp, const unsigned short* __restrict__ wt,
    const float* __restrict__ wsc, const float* __restrict__ psp,
    const float* __restrict__ psn, float* __restrict__ out) {
  __shared__ char Astrip[89088];                // 348 px * 256B
  __shared__ char Bbuf[3][16384];               // 256 oc * 64B per chunk

  const int bid = blockIdx.x;
  const int wg = (bid & 7) * 50 + (bid >> 3);   // bijective XCD swizzle (400=8*50)
  const int b = wg / 25;
  const int tile = wg - b * 25;
  int r0 = (tile * 128) / 56; if (r0 > 52) r0 = 52;

  const int tid = threadIdx.x;
  const int wv = tid >> 6;
  const int l = tid & 63;
  const int wr = wv >> 2, wc = wv & 3;

  // ---- per-m-frag pixel base within strip (tap 0 = top-left)
  int pxb[4];
#pragma unroll
  for (int mi = 0; mi < 4; ++mi) {
    int m = tile * 128 + wr * 64 + mi * 16 + (l & 15);
    if (m > 3135) m = 3135;                      // dead px: clamp (stores masked)
    int rv = m / 56, w = m - rv * 56;
    pxb[mi] = (rv - r0) * 58 + w;
  }
  // ---- B frag read offsets (buf-relative)
  int boffr[4];
#pragma unroll
  for (int ni = 0; ni < 4; ++ni) {
    int row = wc * 64 + ni * 16 + (l & 15);
    boffr[ni] = row * 64 + ((((l >> 4) ^ (row & 3))) << 4);
  }

  // ---- scalars
  float w0s = wsc[0], w1s = wsc[1], w2s = wsc[2], w3s = wsc[3];
  float p0 = psp[0], p1 = psp[1], p2 = psp[2], p3 = psp[3];
  float n0 = psn[0], n1 = psn[1], n2 = psn[2], n3 = psn[3];

  f32x4_t acc[4][4], oacc[4][4];
  const f32x4_t fz = {0.f, 0.f, 0.f, 0.f};
#pragma unroll
  for (int i = 0; i < 4; ++i)
#pragma unroll
    for (int j = 0; j < 4; ++j) { acc[i][j] = fz; oacc[i][j] = fz; }

  const char* xg = (const char*)xp;
  const char* wgp = (const char*)wt;
  const unsigned a_src = (unsigned)((b * 58 + r0) * 58) * 256u;

  // stage A strip for group gg: 5568 chunks, 10-11 per thread (wave-uniform)
#define STAGE_A(gg)                                                            \
  {                                                                            \
    const char* s_ = xg + (unsigned)(gg)*13778944u + a_src;                    \
    _Pragma("unroll")                                                          \
    for (int k_ = 0; k_ < 11; ++k_) {                                          \
      int c_ = tid + (k_ << 9);                                                \
      if (c_ < 5568) {                                                         \
        int px_ = c_ >> 4, ch_ = c_ & 15;                                      \
        g2l16(s_ + px_ * 256 + ((ch_ ^ (px_ & 7)) << 4), Astrip + c_ * 16);    \
      }                                                                        \
    }                                                                          \
  }

  // stage B chunk for unit uu (2 loads/thread)
#define STAGE_B(uu)                                                            \
  {                                                                            \
    const int u_ = (uu);                                                       \
    const int g_ = u_ / 36;                                                    \
    const int r_ = u_ - g_ * 36;                                               \
    const int sg_ = (r_ >= 18) ? 1 : 0;                                        \
    const int r18_ = r_ - (sg_ ? 18 : 0);                                      \
    const char* s_ = wgp + (size_t)((g_ * 2 + sg_) * 256) * 1152 +             \
                     (r18_ >> 1) * 128 + (r18_ & 1) * 64;                      \
    char* d_ = &Bbuf[u_ % 3][0];                                               \
    {                                                                          \
      int i_ = tid, row_ = i_ >> 2;                                            \
      g2l16(s_ + row_ * 1152 + (((i_ & 3) ^ (row_ & 3)) << 4), d_ + i_ * 16);  \
    }                                                                          \
    {                                                                          \
      int i_ = tid + 512, row_ = i_ >> 2;                                      \
      g2l16(s_ + row_ * 1152 + (((i_ & 3) ^ (row_ & 3)) << 4), d_ + i_ * 16);  \
    }                                                                          \
  }

  // ---- prologue
  STAGE_A(0);
  STAGE_B(0);
  STAGE_B(1);

  for (int u = 0; u < 144; ++u) {
    const int g = u / 36;
    const int r36 = u - g * 36;
    if (r36 == 35) { VMCNT0; } else { VMCNT2; }
    BAR;
    MEMPIN;
    const int sgn = (r36 >= 18) ? 1 : 0;
    const int r18 = r36 - (sgn ? 18 : 0);
    const int tap = r18 >> 1, cc = r18 & 1;
    const int tapoff = (tap / 3) * 58 + (tap - (tap / 3) * 3);
    const char* bbuf = &Bbuf[u % 3][0];

    bf16x8_t ahi[4], alo[4], bfr[4];
    const int kb = ((l >> 4) + cc * 4) << 4;     // hl adds +128 (disjoint bit)
#pragma unroll
    for (int mi = 0; mi < 4; ++mi) {
      int px = pxb[mi] + tapoff;
      int base = (px << 8) + (kb ^ ((px & 7) << 4));
      ahi[mi] = *(const bf16x8_t*)(Astrip + base);
      alo[mi] = *(const bf16x8_t*)(Astrip + base + 128);
    }
#pragma unroll
    for (int ni = 0; ni < 4; ++ni)
      bfr[ni] = *(const bf16x8_t*)(bbuf + boffr[ni]);
    MEMPIN;
    if (r36 < 34) { STAGE_B(u + 2); }            // u=142,143 excluded naturally

    __builtin_amdgcn_s_setprio(1);
#pragma unroll
    for (int mi = 0; mi < 4; ++mi)
#pragma unroll
      for (int ni = 0; ni < 4; ++ni) {
        acc[mi][ni] = __builtin_amdgcn_mfma_f32_16x16x32_bf16(ahi[mi], bfr[ni], acc[mi][ni], 0, 0, 0);
        acc[mi][ni] = __builtin_amdgcn_mfma_f32_16x16x32_bf16(alo[mi], bfr[ni], acc[mi][ni], 0, 0, 0);
      }
    __builtin_amdgcn_s_setprio(0);

    // ---- group-sign boundary: quantize psums into oacc
    if ((u % 18) == 17) {
      float sw = (g & 2) ? ((g & 1) ? w3s : w2s) : ((g & 1) ? w1s : w0s);
      float sp = (g & 2) ? ((g & 1) ? p3 : p2) : ((g & 1) ? p1 : p0);
      float sn = (g & 2) ? ((g & 1) ? n3 : n2) : ((g & 1) ? n1 : n0);
      float sq = sgn ? sn : sp;
      float rs = sw / sq;
      float sgnmul = sgn ? -sq : sq;
#pragma unroll
      for (int mi = 0; mi < 4; ++mi)
#pragma unroll
        for (int ni = 0; ni < 4; ++ni)
#pragma unroll
          for (int j = 0; j < 4; ++j) {
            float v = acc[mi][ni][j] * rs;
            v = fminf(fmaxf(v, -128.f), 127.f);
            oacc[mi][ni][j] += sgnmul * rintf(v);
            acc[mi][ni][j] = 0.f;
          }
    }

    // ---- group boundary: publish next group's A strip + deferred B chunks
    if (r36 == 35 && u < 143) {
      BAR;                                       // all waves done reading strip
      STAGE_A(g + 1);
      STAGE_B(u + 1);
      STAGE_B(u + 2);
    }
  }

  // ---- store (dead px masked)
#pragma unroll
  for (int ni = 0; ni < 4; ++ni) {
    int oc = wc * 64 + ni * 16 + (l & 15);
    float* orow = out + ((size_t)(b * 256 + oc)) * 3136;
#pragma unroll
    for (int mi = 0; mi < 4; ++mi) {
      int m0 = tile * 128 + wr * 64 + mi * 16 + ((l >> 4) << 2);
#pragma unroll
      for (int j = 0; j < 4; ++j) {
        int m = m0 + j;
        if (m < 3136) orow[m] = oacc[mi][ni][j];
      }
    }
  }
#undef STAGE_A
#undef STAGE_B
}

// ---------------------------------------------------------------------------
// Fallback (ws too small): direct conv with inline weight quantization.
// ---------------------------------------------------------------------------
__global__ __launch_bounds__(256) void naive_conv(
    const float* __restrict__ x, const float* __restrict__ wgt,
    const float* __restrict__ wsc, const float* __restrict__ psp,
    const float* __restrict__ psn, float* __restrict__ out) {
  int idx = blockIdx.x * 256 + threadIdx.x;
  if (idx >= 12845056) return;
  int b = idx / 802816;
  int r = idx - b * 802816;
  int oc = r / 3136;
  int hw = r - oc * 3136;
  int h = hw / 56, w = hw - (hw / 56) * 56;
  float o = 0.f;
  for (int g = 0; g < 4; ++g) {
    float sw = wsc[g];
    float inv = 1.f / sw;
    float pp = 0.f, pn = 0.f;
    for (int tap = 0; tap < 9; ++tap) {
      int y = h + tap / 3 - 1, xx = w + tap % 3 - 1;
      if (y < 0 || y > 55 || xx < 0 || xx > 55) continue;
      const float* xr = x + (size_t)(b * 256 + g * 64) * 3136 + y * 56 + xx;
      const float* wrr = wgt + (size_t)oc * 2304 + (size_t)(g * 64) * 9 + tap;
      for (int c = 0; c < 64; ++c) {
        float xv = xr[(size_t)c * 3136];
        float rv = wrr[c * 9] * inv;
        pp += xv * rintf(fminf(fmaxf(rv, 0.f), 3.f));
        pn += xv * rintf(fminf(fmaxf(-rv, 0.f), 3.f));
      }
    }
    float sp = psp[g], sn = psn[g];
    o += rintf(fminf(fmaxf(pp * (sw / sp), -128.f), 127.f)) * sp;
    o -= rintf(fminf(fmaxf(pn * (sw / sn), -128.f), 127.f)) * sn;
  }
  out[idx] = o;
}

extern "C" void kernel_launch(void* const* d_in, const int* in_sizes, int n_in,
                              void* d_out, int out_size, void* d_ws, size_t ws_size,
                              hipStream_t stream) {
  const float* x = (const float*)d_in[0];
  const float* wgt = (const float*)d_in[1];
  const float* wsc = (const float*)d_in[2];
  const float* psp = (const float*)d_in[3];
  const float* psn = (const float*)d_in[4];
  float* out = (float*)d_out;

  if (ws_size >= (size_t)XP_BYTES + (size_t)WT_BYTES) {
    unsigned short* xpw = (unsigned short*)d_ws;
    unsigned short* wtw = (unsigned short*)((char*)d_ws + XP_BYTES);
    hipMemsetAsync(d_ws, 0, XP_BYTES, stream);
    prep_x<<<3584, 256, 0, stream>>>(x, (__hip_bfloat16*)xpw);
    prep_w<<<2304, 256, 0, stream>>>(wgt, wsc, (__hip_bfloat16*)wtw);
    conv_mfma<<<400, 512, 0, stream>>>(xpw, wtw, wsc, psp, psn, out);
  } else {
    naive_conv<<<(12845056 + 255) / 256, 256, 0, stream>>>(x, wgt, wsc, psp, psn, out);
  }
}

// Round 5
// 288.021 us; speedup vs baseline: 1.2369x; 1.2369x over previous
//
#include <hip/hip_runtime.h>
#include <hip/hip_bf16.h>

typedef __attribute__((ext_vector_type(8))) short bf16x8_t;
typedef __attribute__((ext_vector_type(4))) float f32x4_t;

#define XP_BYTES 55115776u   // 4*16*58*58*128*2
#define WT_BYTES 2359296u    // 4*2*256*576*2  (hl-dedup'd)

typedef __attribute__((address_space(1))) const unsigned int ga_u32_t;
typedef __attribute__((address_space(3))) unsigned int lds_u32_t;

__device__ __forceinline__ void g2l16(const void* g, void* l) {
  __builtin_amdgcn_global_load_lds((ga_u32_t*)g, (lds_u32_t*)l, 16, 0, 0);
}

// ---------------------------------------------------------------------------
// prep_x: x (16,256,56,56) f32  ->  xp (4,16,58,58,128) bf16, inner = hl*64+c
// borders zeroed by hipMemsetAsync before this kernel.
// ---------------------------------------------------------------------------
__global__ __launch_bounds__(256) void prep_x(const float* __restrict__ x,
                                              __hip_bfloat16* __restrict__ xp) {
  __shared__ float ls[64 * 57];
  int blk = blockIdx.x;            // (g, b, h) : 4*16*56 = 3584
  int g = blk / 896;
  int r = blk - g * 896;
  int b = r / 56;
  int h = r - b * 56;
  int tid = threadIdx.x;
  const float* src = x + (size_t)(b * 256 + g * 64) * 3136 + h * 56;
  for (int i = tid; i < 64 * 56; i += 256) {
    int c = i / 56, w = i - c * 56;
    ls[c * 57 + w] = src[(size_t)c * 3136 + w];
  }
  __syncthreads();
  __hip_bfloat16* dst = xp + ((size_t)((g * 16 + b) * 58 + h + 1) * 58 + 1) * 128;
  int wp = tid >> 7;
  int inner = tid & 127;
  int hl = inner >> 6, c = inner & 63;
  for (int w0 = 0; w0 < 56; w0 += 2) {
    int w = w0 + wp;
    float v = ls[c * 57 + w];
    __hip_bfloat16 hi = __float2bfloat16(v);
    __hip_bfloat16 val = hl ? __float2bfloat16(v - __bfloat162float(hi)) : hi;
    dst[(size_t)w * 128 + inner] = val;
  }
}

// ---------------------------------------------------------------------------
// prep_w: weight (256,256,3,3) f32 -> wt[g][sign][oc 256][tap 9][c 64] bf16
// integer quant levels 0..3 (exact in bf16). No hl duplication (K=576/gs).
// ---------------------------------------------------------------------------
__global__ __launch_bounds__(256) void prep_w(const float* __restrict__ wgt,
                                              const float* __restrict__ wsc,
                                              __hip_bfloat16* __restrict__ wt) {
  int idx = blockIdx.x * 256 + threadIdx.x;   // 589824 = 256oc*256C*9tap
  if (idx >= 589824) return;
  int oc = idx / 2304;
  int r = idx - oc * 2304;
  int C = r / 9;
  int tap = r - C * 9;
  int g = C >> 6, c = C & 63;
  float s = wsc[g];
  float rv = wgt[idx] / s;
  float ip = rintf(fminf(fmaxf(rv, 0.f), 3.f));
  float iN = rintf(fminf(fmaxf(-rv, 0.f), 3.f));
  size_t base_p = (size_t)((g * 2 + 0) * 256 + oc) * 576 + tap * 64 + c;
  size_t base_n = (size_t)((g * 2 + 1) * 256 + oc) * 576 + tap * 64 + c;
  wt[base_p] = __float2bfloat16(ip);
  wt[base_n] = __float2bfloat16(iN);
}

// ---------------------------------------------------------------------------
// Main conv. Grid 784 = 16 b x 49 aligned 64-px tiles. BM=64 px, BN=256 oc.
// 256 thr = 4 waves (1M x 4N), wave 64x64, 2 blocks/CU (LDS exactly 80KB).
// A: 4 xp-rows x 64-px-padded x 256B strip (64KB), restaged per group; all
//    9 taps are LDS offsets; 64-stride => px&7 = (w+tx)&7 (uniform, since
//    56 % 8 == 0) -> conflict-free 8-slot XOR swizzle.
// B: 16KB (g,sign,tap,cc) chunks, single-buffered; slot XOR (row>>1)&3
//    (64B rows: bank = (row&1)*16 + slot*4 -> exactly 2 lanes/bank).
// Unit = (g,sign,tap,cc): 12 ds_read_b128 + 32 MFMA (hl-paired B reuse).
// Per-block vmcnt(0) drains are hidden by the co-resident partner block.
// ---------------------------------------------------------------------------
#define MEMPIN asm volatile("" ::: "memory")
#define BAR __builtin_amdgcn_s_barrier()
#define VMCNT0 asm volatile("s_waitcnt vmcnt(0)" ::: "memory")

__global__ __launch_bounds__(256, 2) void conv_mfma(
    const unsigned short* __restrict__ xp, const unsigned short* __restrict__ wt,
    const float* __restrict__ wsc, const float* __restrict__ psp,
    const float* __restrict__ psn, float* __restrict__ out) {
  __shared__ char Astrip[65536];               // 4 rows x 64 px x 256B
  __shared__ char Bbuf[16384];                 // 256 oc x 64B

  const int bid = blockIdx.x;
  const int wg = (bid & 7) * 98 + (bid >> 3);  // bijective XCD swizzle (784=8*98)
  const int b = wg / 49;
  const int t = wg - b * 49;
  const int r0 = (t << 6) / 56;                // top xp-row of strip

  const int tid = threadIdx.x;
  const int wv = tid >> 6;                     // N quarter
  const int l = tid & 63;

  // ---- A frag pixel bases (strip-relative, 64-px row stride)
  int pxb[4];
#pragma unroll
  for (int mi = 0; mi < 4; ++mi) {
    int m = (t << 6) + mi * 16 + (l & 15);
    int rv = m / 56, w = m - rv * 56;
    pxb[mi] = ((rv - r0) << 6) + w;
  }
  // ---- B frag read offsets
  int boffr[4];
#pragma unroll
  for (int ni = 0; ni < 4; ++ni) {
    int row = (wv << 6) + ni * 16 + (l & 15);
    boffr[ni] = (row << 6) + (((l >> 4) ^ ((row >> 1) & 3)) << 4);
  }

  // ---- scalars preloaded
  float w0s = wsc[0], w1s = wsc[1], w2s = wsc[2], w3s = wsc[3];
  float p0 = psp[0], p1 = psp[1], p2 = psp[2], p3 = psp[3];
  float n0 = psn[0], n1 = psn[1], n2 = psn[2], n3 = psn[3];

  f32x4_t acc[4][4], oacc[4][4];
  const f32x4_t fz = {0.f, 0.f, 0.f, 0.f};
#pragma unroll
  for (int i = 0; i < 4; ++i)
#pragma unroll
    for (int j = 0; j < 4; ++j) { acc[i][j] = fz; oacc[i][j] = fz; }

  const char* xg = (const char*)xp;
  const char* wgp = (const char*)wt;
  const unsigned a_gbbase = (unsigned)((b * 3364 + r0 * 58) * 256);

  // stage the 64KB A strip for group gg (16 loads/thread)
#define STAGE_STRIP(gg)                                                        \
  {                                                                            \
    const char* s_ = xg + (unsigned)(gg)*13778944u + a_gbbase;                 \
    _Pragma("unroll")                                                          \
    for (int k_ = 0; k_ < 16; ++k_) {                                          \
      int idx_ = tid + (k_ << 8);                                              \
      int px_ = idx_ >> 4, sl_ = idx_ & 15;                                    \
      int sr_ = px_ >> 6, xc_ = px_ & 63;                                      \
      g2l16(s_ + (sr_ * 58 + xc_) * 256 +                                      \
                (((sl_ & 8) | ((sl_ & 7) ^ (xc_ & 7))) << 4),                  \
            Astrip + idx_ * 16);                                               \
    }                                                                          \
  }

  // stage the 16KB B chunk for unit uu (4 loads/thread)
#define STAGE_B(uu)                                                            \
  {                                                                            \
    const int u_ = (uu);                                                       \
    const int g_ = u_ / 36;                                                    \
    const int r_ = u_ - g_ * 36;                                               \
    const int sg_ = (r_ >= 18) ? 1 : 0;                                        \
    const int r18_ = r_ - (sg_ ? 18 : 0);                                      \
    const char* s_ = wgp + (size_t)((g_ * 2 + sg_) * 256) * 1152 +             \
                     (r18_ >> 1) * 128 + (r18_ & 1) * 64;                      \
    _Pragma("unroll")                                                          \
    for (int k_ = 0; k_ < 4; ++k_) {                                           \
      int idx_ = tid + (k_ << 8);                                              \
      int row_ = idx_ >> 2, sl_ = idx_ & 3;                                    \
      g2l16(s_ + row_ * 1152 + ((sl_ ^ ((row_ >> 1) & 3)) << 4),               \
            Bbuf + idx_ * 16);                                                 \
    }                                                                          \
  }

  // ---- prologue
  STAGE_STRIP(0);
  STAGE_B(0);

  for (int u = 0; u < 144; ++u) {
    const int g = u / 36;
    const int r36 = u - g * 36;
    const int sgn = (r36 >= 18) ? 1 : 0;
    const int r18 = r36 - (sgn ? 18 : 0);
    const int tap = r18 >> 1, cc = r18 & 1;
    const int ty = tap / 3, tx = tap - ty * 3;
    const int tapoff = (ty << 6) + tx;

    VMCNT0;                                    // strip + B(u) LDS-writes landed
    BAR;
    MEMPIN;

    bf16x8_t ahi[4], alo[4], bfr[4];
    const int kj = (cc << 2) + (l >> 4);       // hi-half chunk index 0..7
#pragma unroll
    for (int mi = 0; mi < 4; ++mi) {
      int px = pxb[mi] + tapoff;
      int base = (px << 8) + ((kj ^ (px & 7)) << 4);
      ahi[mi] = *(const bf16x8_t*)(Astrip + base);
      alo[mi] = *(const bf16x8_t*)(Astrip + base + 128);
    }
#pragma unroll
    for (int ni = 0; ni < 4; ++ni)
      bfr[ni] = *(const bf16x8_t*)(Bbuf + boffr[ni]);
    MEMPIN;
    BAR;                                       // all waves' reads issued
    MEMPIN;

    if (r36 == 35 && u < 143) { STAGE_STRIP(g + 1); }
    if (u + 1 < 144) { STAGE_B(u + 1); }

    __builtin_amdgcn_s_setprio(1);
#pragma unroll
    for (int mi = 0; mi < 4; ++mi)
#pragma unroll
      for (int ni = 0; ni < 4; ++ni) {
        acc[mi][ni] = __builtin_amdgcn_mfma_f32_16x16x32_bf16(ahi[mi], bfr[ni], acc[mi][ni], 0, 0, 0);
        acc[mi][ni] = __builtin_amdgcn_mfma_f32_16x16x32_bf16(alo[mi], bfr[ni], acc[mi][ni], 0, 0, 0);
      }
    __builtin_amdgcn_s_setprio(0);

    // ---- group-sign boundary: quantize psums into oacc
    if (r36 == 17 || r36 == 35) {
      float sw = (g & 2) ? ((g & 1) ? w3s : w2s) : ((g & 1) ? w1s : w0s);
      float sp = (g & 2) ? ((g & 1) ? p3 : p2) : ((g & 1) ? p1 : p0);
      float sn = (g & 2) ? ((g & 1) ? n3 : n2) : ((g & 1) ? n1 : n0);
      float sq = sgn ? sn : sp;
      float rs = sw / sq;
      float sgnmul = sgn ? -sq : sq;
#pragma unroll
      for (int mi = 0; mi < 4; ++mi)
#pragma unroll
        for (int ni = 0; ni < 4; ++ni)
#pragma unroll
          for (int j = 0; j < 4; ++j) {
            float v = acc[mi][ni][j] * rs;
            v = fminf(fmaxf(v, -128.f), 127.f);
            oacc[mi][ni][j] += sgnmul * rintf(v);
            acc[mi][ni][j] = 0.f;
          }
    }
  }

  // ---- store (tiles are image-aligned: no masking needed)
#pragma unroll
  for (int ni = 0; ni < 4; ++ni) {
    int oc = (wv << 6) + ni * 16 + (l & 15);
    float* orow = out + ((size_t)(b * 256 + oc)) * 3136;
#pragma unroll
    for (int mi = 0; mi < 4; ++mi) {
      int m0 = (t << 6) + mi * 16 + ((l >> 4) << 2);
#pragma unroll
      for (int j = 0; j < 4; ++j) {
        orow[m0 + j] = oacc[mi][ni][j];
      }
    }
  }
#undef STAGE_STRIP
#undef STAGE_B
}

// ---------------------------------------------------------------------------
// Fallback (ws too small): direct conv with inline weight quantization.
// ---------------------------------------------------------------------------
__global__ __launch_bounds__(256) void naive_conv(
    const float* __restrict__ x, const float* __restrict__ wgt,
    const float* __restrict__ wsc, const float* __restrict__ psp,
    const float* __restrict__ psn, float* __restrict__ out) {
  int idx = blockIdx.x * 256 + threadIdx.x;
  if (idx >= 12845056) return;
  int b = idx / 802816;
  int r = idx - b * 802816;
  int oc = r / 3136;
  int hw = r - oc * 3136;
  int h = hw / 56, w = hw - (hw / 56) * 56;
  float o = 0.f;
  for (int g = 0; g < 4; ++g) {
    float sw = wsc[g];
    float inv = 1.f / sw;
    float pp = 0.f, pn = 0.f;
    for (int tap = 0; tap < 9; ++tap) {
      int y = h + tap / 3 - 1, xx = w + tap % 3 - 1;
      if (y < 0 || y > 55 || xx < 0 || xx > 55) continue;
      const float* xr = x + (size_t)(b * 256 + g * 64) * 3136 + y * 56 + xx;
      const float* wrr = wgt + (size_t)oc * 2304 + (size_t)(g * 64) * 9 + tap;
      for (int c = 0; c < 64; ++c) {
        float xv = xr[(size_t)c * 3136];
        float rv = wrr[c * 9] * inv;
        pp += xv * rintf(fminf(fmaxf(rv, 0.f), 3.f));
        pn += xv * rintf(fminf(fmaxf(-rv, 0.f), 3.f));
      }
    }
    float sp = psp[g], sn = psn[g];
    o += rintf(fminf(fmaxf(pp * (sw / sp), -128.f), 127.f)) * sp;
    o -= rintf(fminf(fmaxf(pn * (sw / sn), -128.f), 127.f)) * sn;
  }
  out[idx] = o;
}

extern "C" void kernel_launch(void* const* d_in, const int* in_sizes, int n_in,
                              void* d_out, int out_size, void* d_ws, size_t ws_size,
                              hipStream_t stream) {
  const float* x = (const float*)d_in[0];
  const float* wgt = (const float*)d_in[1];
  const float* wsc = (const float*)d_in[2];
  const float* psp = (const float*)d_in[3];
  const float* psn = (const float*)d_in[4];
  float* out = (float*)d_out;

  if (ws_size >= (size_t)XP_BYTES + (size_t)WT_BYTES) {
    unsigned short* xpw = (unsigned short*)d_ws;
    unsigned short* wtw = (unsigned short*)((char*)d_ws + XP_BYTES);
    hipMemsetAsync(d_ws, 0, XP_BYTES, stream);
    prep_x<<<3584, 256, 0, stream>>>(x, (__hip_bfloat16*)xpw);
    prep_w<<<2304, 256, 0, stream>>>(wgt, wsc, (__hip_bfloat16*)wtw);
    conv_mfma<<<784, 256, 0, stream>>>(xpw, wtw, wsc, psp, psn, out);
  } else {
    naive_conv<<<(12845056 + 255) / 256, 256, 0, stream>>>(x, wgt, wsc, psp, psn, out);
  }
}